// Round 1
// baseline (5410.003 us; speedup 1.0000x reference)
//
#include <hip/hip_runtime.h>

#define N_ 384
#define LNEPS 1e-5f

__device__ __forceinline__ float bf2f(unsigned int u) {
    union { unsigned int i; float f; } v; v.i = u << 16; return v.f;
}
__device__ __forceinline__ unsigned short f2bf(float f) {
    union { float f; unsigned int i; } v; v.f = f;
    return (unsigned short)((v.i + 0x7FFFu + ((v.i >> 16) & 1u)) >> 16);
}

// ---------------------------------------------------------------------------
// Kernel 1: LayerNorm + V projection (store transposed bf16) + EG projection
// Block: 256 threads, handles 64 rows (b, r1 in [i0,i0+64), r2 fixed).
// ---------------------------------------------------------------------------
__global__ __launch_bounds__(256) void k1_ln_proj(
    const float* __restrict__ e, const float* __restrict__ mask,
    const float* __restrict__ ln_w, const float* __restrict__ ln_b,
    const float* __restrict__ W_V, const float* __restrict__ b_V,
    const float* __restrict__ W_EG, const float* __restrict__ b_EG,
    unsigned short* __restrict__ VtIn, unsigned short* __restrict__ VtOut,
    float* __restrict__ EGin, float* __restrict__ EGoutT)
{
    __shared__ float s_eln[64][65];   // also aliased as s_eg[64][33] later
    __shared__ float s_wt[160][68];   // Wt[c][l]: transposed weights, 16B-aligned rows

    const int t = threadIdx.x;
    int idx = blockIdx.x;
    const int r2 = idx % N_; idx /= N_;
    const int i0 = (idx % 6) * 64;
    const int b  = idx / 6;

    // stage transposed weights
    for (int x = t; x < 64*128; x += 256) { int l = x >> 7, c = x & 127; s_wt[c][l] = W_V[x]; }
    for (int x = t; x < 64*32;  x += 256) { int l = x >> 5, c = x & 31;  s_wt[128+c][l] = W_EG[x]; }

    // phase 1: LayerNorm (4 threads per row)
    {
        const int rl = t >> 2, q = t & 3;
        const int rw = i0 + rl;
        const float* erow = e + ((size_t)((b*N_ + rw)*N_ + r2))*64 + q*16;
        float ev[16]; float s = 0.f, sq = 0.f;
        #pragma unroll
        for (int j = 0; j < 4; ++j) {
            float4 v = *(const float4*)(erow + j*4);
            ev[4*j]=v.x; ev[4*j+1]=v.y; ev[4*j+2]=v.z; ev[4*j+3]=v.w;
            s += v.x+v.y+v.z+v.w; sq += v.x*v.x+v.y*v.y+v.z*v.z+v.w*v.w;
        }
        s  += __shfl_xor(s, 1);  s  += __shfl_xor(s, 2);
        sq += __shfl_xor(sq, 1); sq += __shfl_xor(sq, 2);
        float mean = s * (1.f/64.f);
        float rstd = rsqrtf(sq*(1.f/64.f) - mean*mean + LNEPS);
        #pragma unroll
        for (int j = 0; j < 16; ++j) {
            int ch = q*16 + j;
            s_eln[rl][ch] = (ev[j]-mean)*rstd*ln_w[ch] + ln_b[ch];
        }
    }
    __syncthreads();

    // phase 2: projections. thread t -> row r=t&63, channel group g=t>>6 (c = 4m+g)
    const int r = t & 63, g = t >> 6;
    const int r1 = i0 + r;
    float er[64];
    #pragma unroll
    for (int l = 0; l < 64; ++l) er[l] = s_eln[r][l];
    __syncthreads();                  // s_eln now dead -> alias as s_eg
    float* s_eg = &s_eln[0][0];       // [64][33]

    const float maskv = mask[(size_t)(b*N_ + r1)*N_ + r2];

    unsigned int pin[2][4] = {{0,0,0,0},{0,0,0,0}};
    unsigned int pot[2][4] = {{0,0,0,0},{0,0,0,0}};

    #pragma unroll
    for (int m = 0; m < 40; ++m) {
        const int c = 4*m + g;
        float acc = 0.f;
        const float* wrow = s_wt[c];
        #pragma unroll
        for (int l4 = 0; l4 < 16; ++l4) {
            float4 w = *(const float4*)(wrow + 4*l4);
            acc += er[4*l4]*w.x + er[4*l4+1]*w.y + er[4*l4+2]*w.z + er[4*l4+3]*w.w;
        }
        if (m < 32) {
            // V channels: c = io*64 + 8*d + hh, hh = g + 4*(m&1), d = (m>>1)&7
            const int d_ = (m >> 1) & 7;
            const int s_ = m & 1;
            float v = acc + b_V[c];
            unsigned int bits = ((unsigned int)f2bf(v)) << ((d_ & 1)*16);
            if (m < 16) pin[s_][d_>>1] |= bits; else pot[s_][d_>>1] |= bits;
        } else {
            const int c2 = c - 128;   // 0..31: Ein, Gin, Eout, Gout (8 each)
            float v = acc + b_EG[c2] + maskv;
            if (((c2 >> 3) & 1) != 0) v = 1.f/(1.f + expf(-v));   // gate channels
            s_eg[r*33 + c2] = v;
        }
    }
    {
        // VtIn[bh][k=r2][r1*8+d]  (einsum 'bjkdh': j=r1 -> col, k=r2 -> row)
        size_t bi0 = ((size_t)((b*8 + g    )*N_ + r2))*3072 + (size_t)r1*8;
        size_t bi1 = ((size_t)((b*8 + g + 4)*N_ + r2))*3072 + (size_t)r1*8;
        uint4 u;
        u.x=pin[0][0]; u.y=pin[0][1]; u.z=pin[0][2]; u.w=pin[0][3];
        *(uint4*)(VtIn + bi0) = u;
        u.x=pin[1][0]; u.y=pin[1][1]; u.z=pin[1][2]; u.w=pin[1][3];
        *(uint4*)(VtIn + bi1) = u;
        // VtOut[bh][k=r1][r2*8+d] (einsum 'bkjdh': k=r1 -> row, j=r2 -> col)
        size_t bo0 = ((size_t)((b*8 + g    )*N_ + r1))*3072 + (size_t)r2*8;
        size_t bo1 = ((size_t)((b*8 + g + 4)*N_ + r1))*3072 + (size_t)r2*8;
        u.x=pot[0][0]; u.y=pot[0][1]; u.z=pot[0][2]; u.w=pot[0][3];
        *(uint4*)(VtOut + bo0) = u;
        u.x=pot[1][0]; u.y=pot[1][1]; u.z=pot[1][2]; u.w=pot[1][3];
        *(uint4*)(VtOut + bo1) = u;
    }
    __syncthreads();
    {
        // cooperative coalesced EG stores
        const int rr = t >> 2, cq = (t & 3) * 4;
        const float* sg = s_eg + rr*33;
        float4 v0; v0.x=sg[cq]; v0.y=sg[cq+1]; v0.z=sg[cq+2]; v0.w=sg[cq+3];
        *(float4*)(EGin + ((size_t)((b*N_ + i0+rr)*N_ + r2))*16 + cq) = v0;
        float4 v1; v1.x=sg[16+cq]; v1.y=sg[16+cq+1]; v1.z=sg[16+cq+2]; v1.w=sg[16+cq+3];
        *(float4*)(EGoutT + ((size_t)((b*N_ + r2)*N_ + i0+rr))*16 + cq) = v1;
    }
}

// ---------------------------------------------------------------------------
// Kernel 2: gated softmax over k. EG layout [b][i][k][16] (E:0-7, G:8-15).
// Writes A[bh][i][k] bf16. One block per (b,i).
// ---------------------------------------------------------------------------
__global__ __launch_bounds__(256) void k2_softmax(
    const float* __restrict__ EG, unsigned short* __restrict__ A)
{
    __shared__ float s[384*17];
    const int t = threadIdx.x;
    const int i = blockIdx.x % N_, b = blockIdx.x / N_;
    const float* base = EG + ((size_t)(b*N_ + i)*N_)*16;
    for (int x = t; x < 6144; x += 256) {
        int k = x >> 4, c = x & 15;
        s[k*17 + c] = base[x];
    }
    __syncthreads();
    const int h = t >> 5, l = t & 31;
    float ev[12];
    float mx = -1e30f;
    #pragma unroll
    for (int j = 0; j < 12; ++j) {
        ev[j] = s[(l + 32*j)*17 + h];
        mx = fmaxf(mx, ev[j]);
    }
    #pragma unroll
    for (int off = 16; off >= 1; off >>= 1) mx = fmaxf(mx, __shfl_xor(mx, off));
    float sum = 0.f;
    #pragma unroll
    for (int j = 0; j < 12; ++j) { ev[j] = expf(ev[j] - mx); sum += ev[j]; }
    #pragma unroll
    for (int off = 16; off >= 1; off >>= 1) sum += __shfl_xor(sum, off);
    const float inv = 1.f / sum;
    unsigned short* arow = A + ((size_t)((b*8 + h)*N_ + i))*N_;
    #pragma unroll
    for (int j = 0; j < 12; ++j) {
        int k = l + 32*j;
        arow[k] = f2bf(ev[j] * inv * s[k*17 + 8 + h]);
    }
}

// ---------------------------------------------------------------------------
// Kernel 3: both einsums (over all 8 heads) + fused W_O projection.
// Block: 256 thr; tile = 16 i x 8 j (64 V-cols), loop io in {in,out}.
// ---------------------------------------------------------------------------
__global__ __launch_bounds__(256) void k3_einsum_proj(
    const unsigned short* __restrict__ A_in, const unsigned short* __restrict__ A_outT,
    const unsigned short* __restrict__ VtIn, const unsigned short* __restrict__ VtOut,
    const float* __restrict__ W_O, const float* __restrict__ b_O,
    float* __restrict__ out)
{
    __shared__ __align__(16) char smem[51200];
    unsigned short* As = (unsigned short*)smem;           // [8][16][32] bf16
    unsigned short* Vs = (unsigned short*)(smem + 8192);  // [8][64][40] bf16 ([h][col][k], pad 40)
    float* sWo = (float*)smem;                            // [128][64] f32 (projection phase)
    float* sC  = (float*)(smem + 32768);                  // [4][16][8][9] f32

    const int t = threadIdx.x;
    const int j0 = blockIdx.x * 8;
    const int i0 = blockIdx.y * 16;
    const int b  = blockIdx.z;

    const int colc = t & 63, ig = t >> 6;        // k-loop mapping
    const int jl = colc >> 3, dd = colc & 7;
    const int ij = t >> 1, half = t & 1;         // projection mapping
    const int pi = ij >> 3, pj = ij & 7;
    const int c0 = half * 32;

    float oacc[32];
    #pragma unroll
    for (int x = 0; x < 32; ++x) oacc[x] = b_O[c0 + x];

    const int sArow = t >> 1, sAhf = t & 1;
    const int sAh = sArow >> 4, sAil = sArow & 15;
    const int sVh = t >> 5, sVkk = t & 31;

    #pragma unroll 1
    for (int io = 0; io < 2; ++io) {
        const unsigned short* Ag = io ? A_outT : A_in;
        const unsigned short* Vg = io ? VtOut  : VtIn;
        float acc[8][4];
        #pragma unroll
        for (int h = 0; h < 8; ++h) {
            #pragma unroll
            for (int q = 0; q < 4; ++q) acc[h][q] = 0.f;
        }

        #pragma unroll 1
        for (int kt = 0; kt < 12; ++kt) {
            const int k0 = kt * 32;
            {   // stage A tile [8][16][32]
                const unsigned short* src = Ag + ((size_t)((b*8 + sAh)*N_ + i0 + sAil))*N_ + k0 + sAhf*16;
                uint4 u0 = *(const uint4*)src;
                uint4 u1 = *(const uint4*)(src + 8);
                *(uint4*)(As + sArow*32 + sAhf*16)     = u0;
                *(uint4*)(As + sArow*32 + sAhf*16 + 8) = u1;
            }
            {   // stage V tile with transpose -> [h][col][k], stride 40
                const unsigned short* src = Vg + ((size_t)((b*8 + sVh)*N_ + k0 + sVkk))*3072 + j0*8;
                unsigned short* dst = Vs + sVh*2560 + sVkk;
                #pragma unroll
                for (int cj = 0; cj < 8; ++cj) {
                    uint4 u = *(const uint4*)(src + cj*8);
                    dst[(cj*8+0)*40] = (unsigned short)(u.x);
                    dst[(cj*8+1)*40] = (unsigned short)(u.x >> 16);
                    dst[(cj*8+2)*40] = (unsigned short)(u.y);
                    dst[(cj*8+3)*40] = (unsigned short)(u.y >> 16);
                    dst[(cj*8+4)*40] = (unsigned short)(u.z);
                    dst[(cj*8+5)*40] = (unsigned short)(u.z >> 16);
                    dst[(cj*8+6)*40] = (unsigned short)(u.w);
                    dst[(cj*8+7)*40] = (unsigned short)(u.w >> 16);
                }
            }
            __syncthreads();
            #pragma unroll
            for (int h = 0; h < 8; ++h) {
                const unsigned short* ap = As + h*512 + (ig*4)*32;
                const unsigned short* vp = Vs + h*2560 + colc*40;
                #pragma unroll
                for (int kg = 0; kg < 4; ++kg) {
                    uint4 vv = *(const uint4*)(vp + kg*8);
                    float vf0 = bf2f(vv.x & 0xFFFFu), vf1 = bf2f(vv.x >> 16);
                    float vf2 = bf2f(vv.y & 0xFFFFu), vf3 = bf2f(vv.y >> 16);
                    float vf4 = bf2f(vv.z & 0xFFFFu), vf5 = bf2f(vv.z >> 16);
                    float vf6 = bf2f(vv.w & 0xFFFFu), vf7 = bf2f(vv.w >> 16);
                    #pragma unroll
                    for (int q = 0; q < 4; ++q) {
                        uint4 aa = *(const uint4*)(ap + q*32 + kg*8);
                        float s1 = bf2f(aa.x & 0xFFFFu)*vf0 + bf2f(aa.x >> 16)*vf1
                                 + bf2f(aa.y & 0xFFFFu)*vf2 + bf2f(aa.y >> 16)*vf3;
                        float s2 = bf2f(aa.z & 0xFFFFu)*vf4 + bf2f(aa.z >> 16)*vf5
                                 + bf2f(aa.w & 0xFFFFu)*vf6 + bf2f(aa.w >> 16)*vf7;
                        acc[h][q] += s1 + s2;
                    }
                }
            }
            __syncthreads();
        }
        // fused projection: O += C[h][i][j][d] * W_O[d*16 + io*8 + h][c]
        for (int x = t; x < 8192; x += 256) sWo[x] = W_O[x];
        #pragma unroll 1
        for (int hp = 0; hp < 2; ++hp) {
            #pragma unroll
            for (int hh = 0; hh < 4; ++hh) {
                #pragma unroll
                for (int q = 0; q < 4; ++q)
                    sC[((hh*16 + ig*4 + q)*8 + jl)*9 + dd] = acc[hp*4 + hh][q];
            }
            __syncthreads();
            #pragma unroll
            for (int hh = 0; hh < 4; ++hh) {
                #pragma unroll
                for (int d = 0; d < 8; ++d) {
                    float cv = sC[((hh*16 + pi)*8 + pj)*9 + d];
                    const float* wr = sWo + (d*16 + io*8 + hp*4 + hh)*64 + c0;
                    #pragma unroll
                    for (int cq = 0; cq < 8; ++cq) {
                        float4 w = *(const float4*)(wr + cq*4);
                        oacc[cq*4+0] += cv*w.x; oacc[cq*4+1] += cv*w.y;
                        oacc[cq*4+2] += cv*w.z; oacc[cq*4+3] += cv*w.w;
                    }
                }
            }
            __syncthreads();
        }
    }
    float* orow = out + ((size_t)((b*N_ + i0 + pi)*N_ + j0 + pj))*64 + c0;
    #pragma unroll
    for (int cq = 0; cq < 8; ++cq) {
        float4 v; v.x=oacc[cq*4]; v.y=oacc[cq*4+1]; v.z=oacc[cq*4+2]; v.w=oacc[cq*4+3];
        *(float4*)(orow + cq*4) = v;
    }
}

// ---------------------------------------------------------------------------
extern "C" void kernel_launch(void* const* d_in, const int* in_sizes, int n_in,
                              void* d_out, int out_size, void* d_ws, size_t ws_size,
                              hipStream_t stream)
{
    const float* e    = (const float*)d_in[0];
    const float* mask = (const float*)d_in[1];
    const float* ln_w = (const float*)d_in[2];
    const float* ln_b = (const float*)d_in[3];
    const float* W_V  = (const float*)d_in[4];
    const float* b_V  = (const float*)d_in[5];
    const float* W_EG = (const float*)d_in[6];
    const float* b_EG = (const float*)d_in[7];
    const float* W_O  = (const float*)d_in[8];
    const float* b_O  = (const float*)d_in[9];
    float* out = (float*)d_out;

    char* ws = (char*)d_ws;
    unsigned short* VtIn   = (unsigned short*)(ws);              // 37,748,736 B
    unsigned short* VtOut  = (unsigned short*)(ws + 37748736);   // 37,748,736 B
    unsigned short* A_in   = (unsigned short*)(ws + 75497472);   //  4,718,592 B
    unsigned short* A_outT = (unsigned short*)(ws + 80216064);   //  4,718,592 B
    float* EGin   = (float*)(ws + 84934656);                     // 18,874,368 B
    float* EGoutT = (float*)(ws + 103809024);                    // 18,874,368 B -> total 122,683,392 B

    hipLaunchKernelGGL(k1_ln_proj, dim3(4608), dim3(256), 0, stream,
                       e, mask, ln_w, ln_b, W_V, b_V, W_EG, b_EG, VtIn, VtOut, EGin, EGoutT);
    hipLaunchKernelGGL(k2_softmax, dim3(768), dim3(256), 0, stream, EGin, A_in);
    hipLaunchKernelGGL(k2_softmax, dim3(768), dim3(256), 0, stream, EGoutT, A_outT);
    hipLaunchKernelGGL(k3_einsum_proj, dim3(48, 24, 2), dim3(256), 0, stream,
                       A_in, A_outT, VtIn, VtOut, W_O, b_O, out);
}

// Round 2
// 322.997 us; speedup vs baseline: 16.7494x; 16.7494x over previous
//
#include <hip/hip_runtime.h>

#define N_ 384
#define LNEPS 1e-5f

typedef __attribute__((ext_vector_type(8))) short bf16x8;
typedef __attribute__((ext_vector_type(4))) float f32x4;

__device__ __forceinline__ float bf2f(unsigned int u) {
    union { unsigned int i; float f; } v; v.i = u << 16; return v.f;
}
__device__ __forceinline__ unsigned short f2bf(float f) {
    union { float f; unsigned int i; } v; v.f = f;
    return (unsigned short)((v.i + 0x7FFFu + ((v.i >> 16) & 1u)) >> 16);
}

// ---------------------------------------------------------------------------
// Kernel 1: LayerNorm + V/EG projections as register-blocked fp32 micro-GEMM.
// Block: 256 threads, 64 rows (b, r1 in [i0,i0+64), r2 fixed).
// Thread (rg,cg) computes rows rg*8..+7 x cols cg*5..+4 => 40 accumulators.
// ---------------------------------------------------------------------------
__global__ __launch_bounds__(256) void k1_ln_proj(
    const float* __restrict__ e, const float* __restrict__ mask,
    const float* __restrict__ ln_w, const float* __restrict__ ln_b,
    const float* __restrict__ W_V, const float* __restrict__ b_V,
    const float* __restrict__ W_EG, const float* __restrict__ b_EG,
    unsigned short* __restrict__ VtIn, unsigned short* __restrict__ VtOut,
    float* __restrict__ EGin, float* __restrict__ EGoutT)
{
    __shared__ float s_elnT[64 * 68];   // [ch][row], stride 68
    __shared__ float s_w[64 * 165];     // [l][c], stride 165; re-used as s_out[row][c]
    __shared__ float s_bias[160];

    const int t = threadIdx.x;
    int idx = blockIdx.x;
    const int r2 = idx % N_; idx /= N_;
    const int i0 = (idx % 6) * 64;
    const int b  = idx / 6;

    // stage weights [l][c] (W_V cols 0..127, W_EG cols 128..159) and biases
    for (int x = t; x < 8192; x += 256) s_w[(x >> 7) * 165 + (x & 127)] = W_V[x];
    for (int x = t; x < 2048; x += 256) s_w[(x >> 5) * 165 + 128 + (x & 31)] = W_EG[x];
    if (t < 160) s_bias[t] = (t < 128) ? b_V[t] : b_EG[t - 128];

    // LayerNorm: 4 threads per row, write transposed
    {
        const int rl = t >> 2, q = t & 3;
        const float* erow = e + ((size_t)((b * N_ + i0 + rl) * N_ + r2)) * 64 + q * 16;
        float ev[16]; float s = 0.f, sq = 0.f;
        #pragma unroll
        for (int j = 0; j < 4; ++j) {
            float4 v = *(const float4*)(erow + j * 4);
            ev[4*j] = v.x; ev[4*j+1] = v.y; ev[4*j+2] = v.z; ev[4*j+3] = v.w;
            s += v.x + v.y + v.z + v.w;
            sq += v.x*v.x + v.y*v.y + v.z*v.z + v.w*v.w;
        }
        s  += __shfl_xor(s, 1);  s  += __shfl_xor(s, 2);
        sq += __shfl_xor(sq, 1); sq += __shfl_xor(sq, 2);
        float mean = s * (1.f / 64.f);
        float rstd = rsqrtf(sq * (1.f / 64.f) - mean * mean + LNEPS);
        #pragma unroll
        for (int j = 0; j < 16; ++j) {
            int ch = q * 16 + j;
            s_elnT[ch * 68 + rl] = (ev[j] - mean) * rstd * ln_w[ch] + ln_b[ch];
        }
    }
    __syncthreads();

    // micro-GEMM: acc[8][5]
    const int rg = t >> 5, cg = t & 31;
    float acc[8][5];
    #pragma unroll
    for (int u = 0; u < 8; ++u)
        #pragma unroll
        for (int v = 0; v < 5; ++v) acc[u][v] = 0.f;

    #pragma unroll 4
    for (int l = 0; l < 64; ++l) {
        float4 a0 = *(const float4*)&s_elnT[l * 68 + rg * 8];
        float4 a1 = *(const float4*)&s_elnT[l * 68 + rg * 8 + 4];
        float av[8] = {a0.x, a0.y, a0.z, a0.w, a1.x, a1.y, a1.z, a1.w};
        float wv[5];
        #pragma unroll
        for (int v = 0; v < 5; ++v) wv[v] = s_w[l * 165 + cg * 5 + v];
        #pragma unroll
        for (int u = 0; u < 8; ++u)
            #pragma unroll
            for (int v = 0; v < 5; ++v) acc[u][v] += av[u] * wv[v];
    }
    __syncthreads();
    float* s_out = s_w;   // [64 rows][165]
    #pragma unroll
    for (int u = 0; u < 8; ++u)
        #pragma unroll
        for (int v = 0; v < 5; ++v) s_out[(rg * 8 + u) * 165 + cg * 5 + v] = acc[u][v];
    __syncthreads();

    // V stores (packed bf16, coalesced, layouts as round-1-verified)
    {
        const int r = t & 63, g = t >> 6;
        const int r1 = i0 + r;
        #pragma unroll
        for (int io = 0; io < 2; ++io) {
            #pragma unroll
            for (int hs = 0; hs < 2; ++hs) {
                const int h = g + hs * 4;
                uint4 u4;
                unsigned int w[4];
                #pragma unroll
                for (int dp = 0; dp < 4; ++dp) {
                    int c0 = io * 64 + (2 * dp) * 8 + h;
                    int c1 = io * 64 + (2 * dp + 1) * 8 + h;
                    float v0 = s_out[r * 165 + c0] + s_bias[c0];
                    float v1 = s_out[r * 165 + c1] + s_bias[c1];
                    w[dp] = (unsigned int)f2bf(v0) | ((unsigned int)f2bf(v1) << 16);
                }
                u4.x = w[0]; u4.y = w[1]; u4.z = w[2]; u4.w = w[3];
                if (io == 0) {
                    // VtIn[bh][k=r2][r1*8+d]
                    *(uint4*)(VtIn + ((size_t)((b * 8 + h) * N_ + r2)) * 3072 + (size_t)r1 * 8) = u4;
                } else {
                    // VtOut[bh][k=r1][r2*8+d]
                    *(uint4*)(VtOut + ((size_t)((b * 8 + h) * N_ + r1)) * 3072 + (size_t)r2 * 8) = u4;
                }
            }
        }
    }
    // EG stores (mask + bias + sigmoid on gates)
    {
        const int rr = t >> 2, cq = (t & 3) * 4;
        const float maskv = mask[(size_t)(b * N_ + i0 + rr) * N_ + r2];
        float4 v0, v1;
        float tmp0[4], tmp1[4];
        #pragma unroll
        for (int u = 0; u < 4; ++u) {
            int c2 = cq + u;                      // 0..15: Ein/Gin
            float x = s_out[rr * 165 + 128 + c2] + s_bias[128 + c2] + maskv;
            if (c2 >= 8) x = 1.f / (1.f + expf(-x));
            tmp0[u] = x;
            int c3 = 16 + cq + u;                 // 16..31: Eout/Gout
            float y = s_out[rr * 165 + 128 + c3] + s_bias[128 + c3] + maskv;
            if ((cq + u) >= 8) y = 1.f / (1.f + expf(-y));
            tmp1[u] = y;
        }
        v0.x = tmp0[0]; v0.y = tmp0[1]; v0.z = tmp0[2]; v0.w = tmp0[3];
        v1.x = tmp1[0]; v1.y = tmp1[1]; v1.z = tmp1[2]; v1.w = tmp1[3];
        *(float4*)(EGin   + ((size_t)((b * N_ + i0 + rr) * N_ + r2)) * 16 + cq) = v0;
        *(float4*)(EGoutT + ((size_t)((b * N_ + r2) * N_ + i0 + rr)) * 16 + cq) = v1;
    }
}

// ---------------------------------------------------------------------------
// Kernel 2: gated softmax over k (unchanged from passing round 1).
// ---------------------------------------------------------------------------
__global__ __launch_bounds__(256) void k2_softmax(
    const float* __restrict__ EG, unsigned short* __restrict__ A)
{
    __shared__ float s[384 * 17];
    const int t = threadIdx.x;
    const int i = blockIdx.x % N_, b = blockIdx.x / N_;
    const float* base = EG + ((size_t)(b * N_ + i) * N_) * 16;
    for (int x = t; x < 6144; x += 256) {
        int k = x >> 4, c = x & 15;
        s[k * 17 + c] = base[x];
    }
    __syncthreads();
    const int h = t >> 5, l = t & 31;
    float ev[12];
    float mx = -1e30f;
    #pragma unroll
    for (int j = 0; j < 12; ++j) {
        ev[j] = s[(l + 32 * j) * 17 + h];
        mx = fmaxf(mx, ev[j]);
    }
    #pragma unroll
    for (int off = 16; off >= 1; off >>= 1) mx = fmaxf(mx, __shfl_xor(mx, off));
    float sum = 0.f;
    #pragma unroll
    for (int j = 0; j < 12; ++j) { ev[j] = expf(ev[j] - mx); sum += ev[j]; }
    #pragma unroll
    for (int off = 16; off >= 1; off >>= 1) sum += __shfl_xor(sum, off);
    const float inv = 1.f / sum;
    unsigned short* arow = A + ((size_t)((b * 8 + h) * N_ + i)) * N_;
    #pragma unroll
    for (int j = 0; j < 12; ++j) {
        int k = l + 32 * j;
        arow[k] = f2bf(ev[j] * inv * s[k * 17 + 8 + h]);
    }
}

// ---------------------------------------------------------------------------
// Kernel 2t: transpose V planes: [plane][k=384][jd=3072] -> [plane][jd][k].
// 64x64 bf16 tiles via LDS with XOR-chunk swizzle.
// ---------------------------------------------------------------------------
__global__ __launch_bounds__(256) void k2t_transpose(
    const unsigned short* __restrict__ VtIn, const unsigned short* __restrict__ VtOut,
    unsigned short* __restrict__ VT2In, unsigned short* __restrict__ VT2Out)
{
    __shared__ unsigned short s[64 * 72];
    const int t = threadIdx.x;
    const int ktile = blockIdx.x % 6, jt = blockIdx.x / 6;
    const int q = blockIdx.y;
    const int arr = blockIdx.z;
    const unsigned short* src = (arr ? VtOut : VtIn) + (size_t)q * 1179648;
    unsigned short* dst = (arr ? VT2Out : VT2In) + (size_t)q * 1179648;
    const int k0 = ktile * 64, jd0 = jt * 64;

    {   // load: rows k, 16 jd per thread; swizzled 16-short chunks
        const int kk = t >> 2, cgq = t & 3;
        const unsigned short* g = src + (size_t)(k0 + kk) * 3072 + jd0 + cgq * 16;
        uint4 u0 = *(const uint4*)g;
        uint4 u1 = *(const uint4*)(g + 8);
        int cp = (cgq ^ (kk & 3)) * 16;
        *(uint4*)&s[kk * 72 + cp] = u0;
        *(uint4*)&s[kk * 72 + cp + 8] = u1;
    }
    __syncthreads();
    {   // gather columns, pack, 32B coalesced stores along k
        const int jj = t & 63, kq = (t >> 6) * 16;
        unsigned int wv[8];
        #pragma unroll
        for (int p = 0; p < 8; ++p) {
            int u0 = 2 * p, u1 = 2 * p + 1;
            unsigned short a = s[(kq + u0) * 72 + (((jj >> 4) ^ (u0 & 3)) << 4) + (jj & 15)];
            unsigned short c = s[(kq + u1) * 72 + (((jj >> 4) ^ (u1 & 3)) << 4) + (jj & 15)];
            wv[p] = (unsigned int)a | ((unsigned int)c << 16);
        }
        unsigned short* o = dst + (size_t)(jd0 + jj) * 384 + k0 + kq;
        uint4 x0; x0.x = wv[0]; x0.y = wv[1]; x0.z = wv[2]; x0.w = wv[3];
        uint4 x1; x1.x = wv[4]; x1.y = wv[5]; x1.z = wv[6]; x1.w = wv[7];
        *(uint4*)o = x0;
        *(uint4*)(o + 8) = x1;
    }
}

// ---------------------------------------------------------------------------
// Kernel 3: batched MFMA GEMM. 32 planes: C[p][i][n] = sum_k A[p][i][k]*B[p][n][k].
// 128x128 tile / block (4 waves, each a 64x64 quadrant), BK=32, bf16 16x16x32.
// ---------------------------------------------------------------------------
__global__ __launch_bounds__(256) void k3_mfma(
    const unsigned short* __restrict__ Aall,   // [32][384][384]
    const unsigned short* __restrict__ Vall,   // [32][3072][384]
    unsigned short* __restrict__ C)            // [32][384][3072]
{
    __shared__ short sA[4096];   // [128 rows][32 k] bf16, 16B-chunk add-swizzled
    __shared__ short sB[4096];

    const int t = threadIdx.x;
    const int n0 = blockIdx.x * 128;
    const int i0 = blockIdx.y * 128;
    const int z  = blockIdx.z;             // plane = io*16 + b*8 + h

    const unsigned short* Ap = Aall + (size_t)z * 147456;
    const unsigned short* Bp = Vall + (size_t)z * 1179648;

    const int l = t & 63;
    const int w = t >> 6;
    const int wr = w >> 1, wc = w & 1;
    const int lrow = l & 15, lk = l >> 4;

    const int sr = t >> 1;                 // staging row 0..127
    const int part = t & 1;

    f32x4 acc[4][4];
    #pragma unroll
    for (int m = 0; m < 4; ++m)
        #pragma unroll
        for (int n = 0; n < 4; ++n) acc[m][n] = (f32x4){0.f, 0.f, 0.f, 0.f};

    #pragma unroll 2
    for (int kt = 0; kt < 12; ++kt) {
        const int k0 = kt * 32;
        const unsigned short* ga = Ap + (size_t)(i0 + sr) * 384 + k0 + part * 16;
        const unsigned short* gb = Bp + (size_t)(n0 + sr) * 384 + k0 + part * 16;
        uint4 va0 = *(const uint4*)ga;
        uint4 va1 = *(const uint4*)(ga + 8);
        uint4 vb0 = *(const uint4*)gb;
        uint4 vb1 = *(const uint4*)(gb + 8);
        int c0_ = ((part * 2 + 0) + (sr >> 1)) & 3;
        int c1_ = ((part * 2 + 1) + (sr >> 1)) & 3;
        *(uint4*)((char*)sA + sr * 64 + c0_ * 16) = va0;
        *(uint4*)((char*)sA + sr * 64 + c1_ * 16) = va1;
        *(uint4*)((char*)sB + sr * 64 + c0_ * 16) = vb0;
        *(uint4*)((char*)sB + sr * 64 + c1_ * 16) = vb1;
        __syncthreads();

        bf16x8 av[4], bv[4];
        #pragma unroll
        for (int m = 0; m < 4; ++m) {
            int row = wr * 64 + m * 16 + lrow;
            int ck = (lk + (row >> 1)) & 3;
            av[m] = *(const bf16x8*)((const char*)sA + row * 64 + ck * 16);
        }
        #pragma unroll
        for (int n = 0; n < 4; ++n) {
            int row = wc * 64 + n * 16 + lrow;
            int ck = (lk + (row >> 1)) & 3;
            bv[n] = *(const bf16x8*)((const char*)sB + row * 64 + ck * 16);
        }
        #pragma unroll
        for (int m = 0; m < 4; ++m)
            #pragma unroll
            for (int n = 0; n < 4; ++n)
                acc[m][n] = __builtin_amdgcn_mfma_f32_16x16x32_bf16(av[m], bv[n], acc[m][n], 0, 0, 0);
        __syncthreads();
    }

    // epilogue: D row=(l>>4)*4+q, col=l&15
    unsigned short* Cp = C + (size_t)z * 1179648;
    #pragma unroll
    for (int m = 0; m < 4; ++m) {
        #pragma unroll
        for (int qq = 0; qq < 4; ++qq) {
            int row = i0 + wr * 64 + m * 16 + (l >> 4) * 4 + qq;
            unsigned short* crow = Cp + (size_t)row * 3072 + n0 + wc * 64 + (l & 15);
            #pragma unroll
            for (int n = 0; n < 4; ++n) crow[n * 16] = f2bf(acc[m][n][qq]);
        }
    }
}

// ---------------------------------------------------------------------------
// Kernel 4: out[b,i,j,:] = b_O + sum_c Cgather(b,i,j,c) * W_O[c][:], fp32 W_O.
// Block: (jt, i, b); 128 j x 64 ch per block; thread: 2 j x 16 ch.
// ---------------------------------------------------------------------------
__global__ __launch_bounds__(256) void k4_proj(
    const unsigned short* __restrict__ C, const float* __restrict__ W_O,
    const float* __restrict__ b_O, float* __restrict__ out)
{
    __shared__ float s_w[8192];             // [128][64]
    __shared__ unsigned short s_c[20480];   // [16 p][128 j][10 (8 d + pad)]
    const int t = threadIdx.x;
    const int jt = blockIdx.x;              // 0..2
    const int i  = blockIdx.y;              // 0..383
    const int b  = blockIdx.z;              // 0..1

    for (int x = t; x < 8192; x += 256) s_w[x] = W_O[x];
    {
        unsigned int* s_c32 = (unsigned int*)s_c;
        #pragma unroll
        for (int rep = 0; rep < 8; ++rep) {
            int flat = rep * 256 + t;
            int p = flat >> 7, jj = flat & 127;
            int plane = b * 8 + (p & 7) + (p >> 3) * 16;
            uint4 v = *(const uint4*)(C + (size_t)plane * 1179648 + (size_t)i * 3072 + jt * 1024 + jj * 8);
            int base = p * 640 + jj * 5;
            s_c32[base] = v.x; s_c32[base + 1] = v.y; s_c32[base + 2] = v.z; s_c32[base + 3] = v.w;
        }
    }
    __syncthreads();

    const int jg = t & 63, cg = t >> 6;
    const int chb = cg * 16;
    float acc0[16], acc1[16];
    #pragma unroll
    for (int u = 0; u < 16; ++u) { float bb = b_O[chb + u]; acc0[u] = bb; acc1[u] = bb; }

    #pragma unroll 4
    for (int c = 0; c < 128; ++c) {
        const int p = c & 15, d = c >> 4;
        const int sbase = p * 1280 + (jg * 2) * 10 + d;
        float v0 = bf2f((unsigned int)s_c[sbase]);
        float v1 = bf2f((unsigned int)s_c[sbase + 10]);
        const float* wrp = s_w + c * 64 + chb;
        #pragma unroll
        for (int u4 = 0; u4 < 4; ++u4) {
            float4 wv = *(const float4*)(wrp + u4 * 4);
            acc0[u4*4+0] += v0 * wv.x; acc0[u4*4+1] += v0 * wv.y;
            acc0[u4*4+2] += v0 * wv.z; acc0[u4*4+3] += v0 * wv.w;
            acc1[u4*4+0] += v1 * wv.x; acc1[u4*4+1] += v1 * wv.y;
            acc1[u4*4+2] += v1 * wv.z; acc1[u4*4+3] += v1 * wv.w;
        }
    }
    float* o0 = out + ((size_t)(b * N_ + i) * N_ + jt * 128 + jg * 2) * 64 + chb;
    #pragma unroll
    for (int u4 = 0; u4 < 4; ++u4) {
        float4 a; a.x = acc0[u4*4]; a.y = acc0[u4*4+1]; a.z = acc0[u4*4+2]; a.w = acc0[u4*4+3];
        *(float4*)(o0 + u4 * 4) = a;
        float4 c4; c4.x = acc1[u4*4]; c4.y = acc1[u4*4+1]; c4.z = acc1[u4*4+2]; c4.w = acc1[u4*4+3];
        *(float4*)(o0 + 64 + u4 * 4) = c4;
    }
}

// ---------------------------------------------------------------------------
extern "C" void kernel_launch(void* const* d_in, const int* in_sizes, int n_in,
                              void* d_out, int out_size, void* d_ws, size_t ws_size,
                              hipStream_t stream)
{
    const float* e    = (const float*)d_in[0];
    const float* mask = (const float*)d_in[1];
    const float* ln_w = (const float*)d_in[2];
    const float* ln_b = (const float*)d_in[3];
    const float* W_V  = (const float*)d_in[4];
    const float* b_V  = (const float*)d_in[5];
    const float* W_EG = (const float*)d_in[6];
    const float* b_EG = (const float*)d_in[7];
    const float* W_O  = (const float*)d_in[8];
    const float* b_O  = (const float*)d_in[9];
    float* out = (float*)d_out;

    char* ws = (char*)d_ws;
    // Layout (bytes):
    unsigned short* VtIn   = (unsigned short*)(ws);               // 37,748,736
    unsigned short* VtOut  = (unsigned short*)(ws + 37748736);    // 37,748,736
    unsigned short* A_in   = (unsigned short*)(ws + 75497472);    //  4,718,592
    unsigned short* A_outT = (unsigned short*)(ws + 80216064);    //  4,718,592 (contiguous after A_in)
    float* EGin   = (float*)(ws + 84934656);                      // 18,874,368
    float* EGoutT = (float*)(ws + 103809024);                     // 18,874,368
    // after k2: EG region dead -> VT2In overlays it; VT2Out fresh
    unsigned short* VT2In  = (unsigned short*)(ws + 84934656);    // 37,748,736
    unsigned short* VT2Out = (unsigned short*)(ws + 122683392);   // 37,748,736  (total 160,432,128)
    // after k2t: Vt region dead -> C overlays VtIn+VtOut (75,497,472)
    unsigned short* Cws    = (unsigned short*)(ws);

    hipLaunchKernelGGL(k1_ln_proj, dim3(4608), dim3(256), 0, stream,
                       e, mask, ln_w, ln_b, W_V, b_V, W_EG, b_EG, VtIn, VtOut, EGin, EGoutT);
    hipLaunchKernelGGL(k2_softmax, dim3(768), dim3(256), 0, stream, EGin, A_in);
    hipLaunchKernelGGL(k2_softmax, dim3(768), dim3(256), 0, stream, EGoutT, A_outT);
    hipLaunchKernelGGL(k2t_transpose, dim3(288, 16, 2), dim3(256), 0, stream,
                       VtIn, VtOut, VT2In, VT2Out);
    hipLaunchKernelGGL(k3_mfma, dim3(24, 3, 32), dim3(256), 0, stream,
                       A_in, VT2In, Cws);
    hipLaunchKernelGGL(k4_proj, dim3(3, 384, 2), dim3(256), 0, stream,
                       Cws, W_O, b_O, out);
}

// Round 6
// 312.809 us; speedup vs baseline: 17.2949x; 1.0326x over previous
//
#include <hip/hip_runtime.h>

#define N_ 384
#define LNEPS 1e-5f

typedef __attribute__((ext_vector_type(8))) short bf16x8;
typedef __attribute__((ext_vector_type(4))) float f32x4;

__device__ __forceinline__ float bf2f(unsigned int u) {
    union { unsigned int i; float f; } v; v.i = u << 16; return v.f;
}
__device__ __forceinline__ unsigned short f2bf(float f) {
    union { float f; unsigned int i; } v; v.f = f;
    return (unsigned short)((v.i + 0x7FFFu + ((v.i >> 16) & 1u)) >> 16);
}
__device__ __forceinline__ void gload16(const void* g, void* l) {
    __builtin_amdgcn_global_load_lds(
        (const __attribute__((address_space(1))) void*)g,
        (__attribute__((address_space(3))) void*)l, 16, 0, 0);
}

// ---------------------------------------------------------------------------
// Kernel 1: LayerNorm + V/EG projections as register-blocked fp32 micro-GEMM.
// (round-2-verified verbatim)
// ---------------------------------------------------------------------------
__global__ __launch_bounds__(256) void k1_ln_proj(
    const float* __restrict__ e, const float* __restrict__ mask,
    const float* __restrict__ ln_w, const float* __restrict__ ln_b,
    const float* __restrict__ W_V, const float* __restrict__ b_V,
    const float* __restrict__ W_EG, const float* __restrict__ b_EG,
    unsigned short* __restrict__ VtIn, unsigned short* __restrict__ VtOut,
    float* __restrict__ EGin, float* __restrict__ EGoutT)
{
    __shared__ float s_elnT[64 * 68];   // [ch][row], stride 68
    __shared__ float s_w[64 * 165];     // [l][c], stride 165; re-used as s_out[row][c]
    __shared__ float s_bias[160];

    const int t = threadIdx.x;
    int idx = blockIdx.x;
    const int r2 = idx % N_; idx /= N_;
    const int i0 = (idx % 6) * 64;
    const int b  = idx / 6;

    for (int x = t; x < 8192; x += 256) s_w[(x >> 7) * 165 + (x & 127)] = W_V[x];
    for (int x = t; x < 2048; x += 256) s_w[(x >> 5) * 165 + 128 + (x & 31)] = W_EG[x];
    if (t < 160) s_bias[t] = (t < 128) ? b_V[t] : b_EG[t - 128];

    // LayerNorm: 4 threads per row, write transposed
    {
        const int rl = t >> 2, q = t & 3;
        const float* erow = e + ((size_t)((b * N_ + i0 + rl) * N_ + r2)) * 64 + q * 16;
        float ev[16]; float s = 0.f, sq = 0.f;
        #pragma unroll
        for (int j = 0; j < 4; ++j) {
            float4 v = *(const float4*)(erow + j * 4);
            ev[4*j] = v.x; ev[4*j+1] = v.y; ev[4*j+2] = v.z; ev[4*j+3] = v.w;
            s += v.x + v.y + v.z + v.w;
            sq += v.x*v.x + v.y*v.y + v.z*v.z + v.w*v.w;
        }
        s  += __shfl_xor(s, 1);  s  += __shfl_xor(s, 2);
        sq += __shfl_xor(sq, 1); sq += __shfl_xor(sq, 2);
        float mean = s * (1.f / 64.f);
        float rstd = rsqrtf(sq * (1.f / 64.f) - mean * mean + LNEPS);
        #pragma unroll
        for (int j = 0; j < 16; ++j) {
            int ch = q * 16 + j;
            s_elnT[ch * 68 + rl] = (ev[j] - mean) * rstd * ln_w[ch] + ln_b[ch];
        }
    }
    __syncthreads();

    // micro-GEMM: acc[8][5]
    const int rg = t >> 5, cg = t & 31;
    float acc[8][5];
    #pragma unroll
    for (int u = 0; u < 8; ++u)
        #pragma unroll
        for (int v = 0; v < 5; ++v) acc[u][v] = 0.f;

    #pragma unroll 4
    for (int l = 0; l < 64; ++l) {
        float4 a0 = *(const float4*)&s_elnT[l * 68 + rg * 8];
        float4 a1 = *(const float4*)&s_elnT[l * 68 + rg * 8 + 4];
        float av[8] = {a0.x, a0.y, a0.z, a0.w, a1.x, a1.y, a1.z, a1.w};
        float wv[5];
        #pragma unroll
        for (int v = 0; v < 5; ++v) wv[v] = s_w[l * 165 + cg * 5 + v];
        #pragma unroll
        for (int u = 0; u < 8; ++u)
            #pragma unroll
            for (int v = 0; v < 5; ++v) acc[u][v] += av[u] * wv[v];
    }
    __syncthreads();
    float* s_out = s_w;   // [64 rows][165]
    #pragma unroll
    for (int u = 0; u < 8; ++u)
        #pragma unroll
        for (int v = 0; v < 5; ++v) s_out[(rg * 8 + u) * 165 + cg * 5 + v] = acc[u][v];
    __syncthreads();

    // V stores (packed bf16, coalesced)
    {
        const int r = t & 63, g = t >> 6;
        const int r1 = i0 + r;
        #pragma unroll
        for (int io = 0; io < 2; ++io) {
            #pragma unroll
            for (int hs = 0; hs < 2; ++hs) {
                const int h = g + hs * 4;
                uint4 u4;
                unsigned int w[4];
                #pragma unroll
                for (int dp = 0; dp < 4; ++dp) {
                    int c0 = io * 64 + (2 * dp) * 8 + h;
                    int c1 = io * 64 + (2 * dp + 1) * 8 + h;
                    float v0 = s_out[r * 165 + c0] + s_bias[c0];
                    float v1 = s_out[r * 165 + c1] + s_bias[c1];
                    w[dp] = (unsigned int)f2bf(v0) | ((unsigned int)f2bf(v1) << 16);
                }
                u4.x = w[0]; u4.y = w[1]; u4.z = w[2]; u4.w = w[3];
                if (io == 0) {
                    *(uint4*)(VtIn + ((size_t)((b * 8 + h) * N_ + r2)) * 3072 + (size_t)r1 * 8) = u4;
                } else {
                    *(uint4*)(VtOut + ((size_t)((b * 8 + h) * N_ + r1)) * 3072 + (size_t)r2 * 8) = u4;
                }
            }
        }
    }
    // EG stores (mask + bias + sigmoid on gates)
    {
        const int rr = t >> 2, cq = (t & 3) * 4;
        const float maskv = mask[(size_t)(b * N_ + i0 + rr) * N_ + r2];
        float4 v0, v1;
        float tmp0[4], tmp1[4];
        #pragma unroll
        for (int u = 0; u < 4; ++u) {
            int c2 = cq + u;
            float x = s_out[rr * 165 + 128 + c2] + s_bias[128 + c2] + maskv;
            if (c2 >= 8) x = 1.f / (1.f + expf(-x));
            tmp0[u] = x;
            int c3 = 16 + cq + u;
            float y = s_out[rr * 165 + 128 + c3] + s_bias[128 + c3] + maskv;
            if ((cq + u) >= 8) y = 1.f / (1.f + expf(-y));
            tmp1[u] = y;
        }
        v0.x = tmp0[0]; v0.y = tmp0[1]; v0.z = tmp0[2]; v0.w = tmp0[3];
        v1.x = tmp1[0]; v1.y = tmp1[1]; v1.z = tmp1[2]; v1.w = tmp1[3];
        *(float4*)(EGin   + ((size_t)((b * N_ + i0 + rr) * N_ + r2)) * 16 + cq) = v0;
        *(float4*)(EGoutT + ((size_t)((b * N_ + r2) * N_ + i0 + rr)) * 16 + cq) = v1;
    }
}

// ---------------------------------------------------------------------------
// Kernel 2: gated softmax over k (verified).
// ---------------------------------------------------------------------------
__global__ __launch_bounds__(256) void k2_softmax(
    const float* __restrict__ EG, unsigned short* __restrict__ A)
{
    __shared__ float s[384 * 17];
    const int t = threadIdx.x;
    const int i = blockIdx.x % N_, b = blockIdx.x / N_;
    const float* base = EG + ((size_t)(b * N_ + i) * N_) * 16;
    for (int x = t; x < 6144; x += 256) {
        int k = x >> 4, c = x & 15;
        s[k * 17 + c] = base[x];
    }
    __syncthreads();
    const int h = t >> 5, l = t & 31;
    float ev[12];
    float mx = -1e30f;
    #pragma unroll
    for (int j = 0; j < 12; ++j) {
        ev[j] = s[(l + 32 * j) * 17 + h];
        mx = fmaxf(mx, ev[j]);
    }
    #pragma unroll
    for (int off = 16; off >= 1; off >>= 1) mx = fmaxf(mx, __shfl_xor(mx, off));
    float sum = 0.f;
    #pragma unroll
    for (int j = 0; j < 12; ++j) { ev[j] = expf(ev[j] - mx); sum += ev[j]; }
    #pragma unroll
    for (int off = 16; off >= 1; off >>= 1) sum += __shfl_xor(sum, off);
    const float inv = 1.f / sum;
    unsigned short* arow = A + ((size_t)((b * 8 + h) * N_ + i)) * N_;
    #pragma unroll
    for (int j = 0; j < 12; ++j) {
        int k = l + 32 * j;
        arow[k] = f2bf(ev[j] * inv * s[k * 17 + 8 + h]);
    }
}

// ---------------------------------------------------------------------------
// Kernel 2t: transpose V planes: [plane][k=384][jd=3072] -> [plane][jd][k].
// (round-2-verified verbatim)
// ---------------------------------------------------------------------------
__global__ __launch_bounds__(256) void k2t_transpose(
    const unsigned short* __restrict__ VtIn, const unsigned short* __restrict__ VtOut,
    unsigned short* __restrict__ VT2In, unsigned short* __restrict__ VT2Out)
{
    __shared__ unsigned short s[64 * 72];
    const int t = threadIdx.x;
    const int ktile = blockIdx.x % 6, jt = blockIdx.x / 6;
    const int q = blockIdx.y;
    const int arr = blockIdx.z;
    const unsigned short* src = (arr ? VtOut : VtIn) + (size_t)q * 1179648;
    unsigned short* dst = (arr ? VT2Out : VT2In) + (size_t)q * 1179648;
    const int k0 = ktile * 64, jd0 = jt * 64;

    {
        const int kk = t >> 2, cgq = t & 3;
        const unsigned short* g = src + (size_t)(k0 + kk) * 3072 + jd0 + cgq * 16;
        uint4 u0 = *(const uint4*)g;
        uint4 u1 = *(const uint4*)(g + 8);
        int cp = (cgq ^ (kk & 3)) * 16;
        *(uint4*)&s[kk * 72 + cp] = u0;
        *(uint4*)&s[kk * 72 + cp + 8] = u1;
    }
    __syncthreads();
    {
        const int jj = t & 63, kq = (t >> 6) * 16;
        unsigned int wv[8];
        #pragma unroll
        for (int p = 0; p < 8; ++p) {
            int u0 = 2 * p, u1 = 2 * p + 1;
            unsigned short a = s[(kq + u0) * 72 + (((jj >> 4) ^ (u0 & 3)) << 4) + (jj & 15)];
            unsigned short c = s[(kq + u1) * 72 + (((jj >> 4) ^ (u1 & 3)) << 4) + (jj & 15)];
            wv[p] = (unsigned int)a | ((unsigned int)c << 16);
        }
        unsigned short* o = dst + (size_t)(jd0 + jj) * 384 + k0 + kq;
        uint4 x0; x0.x = wv[0]; x0.y = wv[1]; x0.z = wv[2]; x0.w = wv[3];
        uint4 x1; x1.x = wv[4]; x1.y = wv[5]; x1.z = wv[6]; x1.w = wv[7];
        *(uint4*)o = x0;
        *(uint4*)(o + 8) = x1;
    }
}

// ---------------------------------------------------------------------------
// Kernel 3: batched MFMA GEMM, BK=64, global_load_lds staging (value-identical
// to the round-2 k3 — exonerated by the round-4/5 identical-absmax evidence).
// ---------------------------------------------------------------------------
__global__ __launch_bounds__(256) void k3_mfma(
    const unsigned short* __restrict__ Aall,   // [32][384][384]
    const unsigned short* __restrict__ Vall,   // [32][3072][384]
    unsigned short* __restrict__ C)            // [32][384][3072]
{
    __shared__ __align__(16) short sAB[16384];   // sA [128][64] + sB [128][64]
    short* sA = sAB;
    short* sB = sAB + 8192;

    const int t = threadIdx.x;
    const int n0 = blockIdx.x * 128;
    const int i0 = blockIdx.y * 128;
    const int z  = blockIdx.z;

    const unsigned short* Ap = Aall + (size_t)z * 147456;
    const unsigned short* Bp = Vall + (size_t)z * 1179648;

    const int l = t & 63;
    const int w = t >> 6;
    const int wr = w >> 1, wc = w & 1;
    const int l15 = l & 15, lq = l >> 4;
    const int srow = l >> 3, schunk = (l & 7) ^ (l >> 3);

    f32x4 acc[4][4];
    #pragma unroll
    for (int mi = 0; mi < 4; ++mi)
        #pragma unroll
        for (int ni = 0; ni < 4; ++ni) acc[mi][ni] = (f32x4){0.f, 0.f, 0.f, 0.f};

    #pragma unroll 1
    for (int kt = 0; kt < 6; ++kt) {
        const int k0 = kt * 64;
        #pragma unroll
        for (int i = 0; i < 4; ++i) {
            int rbase = w * 32 + i * 8;
            gload16(Ap + (size_t)(i0 + rbase + srow) * 384 + k0 + schunk * 8,
                    (char*)sA + rbase * 128);
            gload16(Bp + (size_t)(n0 + rbase + srow) * 384 + k0 + schunk * 8,
                    (char*)sB + rbase * 128);
        }
        __syncthreads();

        bf16x8 av[4][2], bv[4][2];
        #pragma unroll
        for (int mi = 0; mi < 4; ++mi) {
            int row = wr * 64 + mi * 16 + l15;
            #pragma unroll
            for (int ks = 0; ks < 2; ++ks) {
                int kc = ks * 4 + lq;
                av[mi][ks] = *(const bf16x8*)((const char*)sA + row * 128 + ((kc ^ (row & 7)) << 4));
            }
        }
        #pragma unroll
        for (int ni = 0; ni < 4; ++ni) {
            int row = wc * 64 + ni * 16 + l15;
            #pragma unroll
            for (int ks = 0; ks < 2; ++ks) {
                int kc = ks * 4 + lq;
                bv[ni][ks] = *(const bf16x8*)((const char*)sB + row * 128 + ((kc ^ (row & 7)) << 4));
            }
        }
        #pragma unroll
        for (int mi = 0; mi < 4; ++mi)
            #pragma unroll
            for (int ni = 0; ni < 4; ++ni) {
                acc[mi][ni] = __builtin_amdgcn_mfma_f32_16x16x32_bf16(av[mi][0], bv[ni][0], acc[mi][ni], 0, 0, 0);
                acc[mi][ni] = __builtin_amdgcn_mfma_f32_16x16x32_bf16(av[mi][1], bv[ni][1], acc[mi][ni], 0, 0, 0);
            }
        __syncthreads();
    }

    unsigned short* Cp = C + (size_t)z * 1179648;
    #pragma unroll
    for (int mi = 0; mi < 4; ++mi) {
        #pragma unroll
        for (int qq = 0; qq < 4; ++qq) {
            int row = i0 + wr * 64 + mi * 16 + lq * 4 + qq;
            unsigned short* crow = Cp + (size_t)row * 3072 + n0 + wc * 64 + l15;
            #pragma unroll
            for (int ni = 0; ni < 4; ++ni) crow[ni * 16] = f2bf(acc[mi][ni][qq]);
        }
    }
}

// ---------------------------------------------------------------------------
// Kernel 4: out = b_O + C(gathered) @ W_O (fp32). (verified)
// ---------------------------------------------------------------------------
__global__ __launch_bounds__(256) void k4_proj(
    const unsigned short* __restrict__ C, const float* __restrict__ W_O,
    const float* __restrict__ b_O, float* __restrict__ out)
{
    __shared__ float s_w[8192];             // [128][64]
    __shared__ unsigned short s_c[20480];   // [16 p][128 j][10]
    const int t = threadIdx.x;
    const int jt = blockIdx.x;
    const int i  = blockIdx.y;
    const int b  = blockIdx.z;

    for (int x = t; x < 8192; x += 256) s_w[x] = W_O[x];
    {
        unsigned int* s_c32 = (unsigned int*)s_c;
        #pragma unroll
        for (int rep = 0; rep < 8; ++rep) {
            int flat = rep * 256 + t;
            int p = flat >> 7, jj = flat & 127;
            int plane = b * 8 + (p & 7) + (p >> 3) * 16;
            uint4 v = *(const uint4*)(C + (size_t)plane * 1179648 + (size_t)i * 3072 + jt * 1024 + jj * 8);
            int base = p * 640 + jj * 5;
            s_c32[base] = v.x; s_c32[base + 1] = v.y; s_c32[base + 2] = v.z; s_c32[base + 3] = v.w;
        }
    }
    __syncthreads();

    const int jg = t & 63, cg = t >> 6;
    const int chb = cg * 16;
    float acc0[16], acc1[16];
    #pragma unroll
    for (int u = 0; u < 16; ++u) { float bb = b_O[chb + u]; acc0[u] = bb; acc1[u] = bb; }

    #pragma unroll 4
    for (int c = 0; c < 128; ++c) {
        const int p = c & 15, d = c >> 4;
        const int sbase = p * 1280 + (jg * 2) * 10 + d;
        float v0 = bf2f((unsigned int)s_c[sbase]);
        float v1 = bf2f((unsigned int)s_c[sbase + 10]);
        const float* wrp = s_w + c * 64 + chb;
        #pragma unroll
        for (int u4 = 0; u4 < 4; ++u4) {
            float4 wv = *(const float4*)(wrp + u4 * 4);
            acc0[u4*4+0] += v0 * wv.x; acc0[u4*4+1] += v0 * wv.y;
            acc0[u4*4+2] += v0 * wv.z; acc0[u4*4+3] += v0 * wv.w;
            acc1[u4*4+0] += v1 * wv.x; acc1[u4*4+1] += v1 * wv.y;
            acc1[u4*4+2] += v1 * wv.z; acc1[u4*4+3] += v1 * wv.w;
        }
    }
    float* o0 = out + ((size_t)(b * N_ + i) * N_ + jt * 128 + jg * 2) * 64 + chb;
    #pragma unroll
    for (int u4 = 0; u4 < 4; ++u4) {
        float4 a; a.x = acc0[u4*4]; a.y = acc0[u4*4+1]; a.z = acc0[u4*4+2]; a.w = acc0[u4*4+3];
        *(float4*)(o0 + u4 * 4) = a;
        float4 c4; c4.x = acc1[u4*4]; c4.y = acc1[u4*4+1]; c4.z = acc1[u4*4+2]; c4.w = acc1[u4*4+3];
        *(float4*)(o0 + 64 + u4 * 4) = c4;
    }
}

// ---------------------------------------------------------------------------
extern "C" void kernel_launch(void* const* d_in, const int* in_sizes, int n_in,
                              void* d_out, int out_size, void* d_ws, size_t ws_size,
                              hipStream_t stream)
{
    const float* e    = (const float*)d_in[0];
    const float* mask = (const float*)d_in[1];
    const float* ln_w = (const float*)d_in[2];
    const float* ln_b = (const float*)d_in[3];
    const float* W_V  = (const float*)d_in[4];
    const float* b_V  = (const float*)d_in[5];
    const float* W_EG = (const float*)d_in[6];
    const float* b_EG = (const float*)d_in[7];
    const float* W_O  = (const float*)d_in[8];
    const float* b_O  = (const float*)d_in[9];
    float* out = (float*)d_out;

    char* ws = (char*)d_ws;
    // round-2-verified layout:
    unsigned short* VtIn   = (unsigned short*)(ws);               // 37,748,736
    unsigned short* VtOut  = (unsigned short*)(ws + 37748736);    // 37,748,736
    unsigned short* A_in   = (unsigned short*)(ws + 75497472);    //  4,718,592
    unsigned short* A_outT = (unsigned short*)(ws + 80216064);    //  4,718,592 (contiguous after A_in)
    float* EGin   = (float*)(ws + 84934656);                      // 18,874,368 (dead after k2)
    float* EGoutT = (float*)(ws + 103809024);                     // 18,874,368 (dead after k2)
    // after k2: EG region dead -> VT2In overlays it; VT2Out fresh (contiguous)
    unsigned short* VT2In  = (unsigned short*)(ws + 84934656);    // 37,748,736
    unsigned short* VT2Out = (unsigned short*)(ws + 122683392);   // 37,748,736
    // after k2t: Vt region dead -> C overlays VtIn+VtOut
    unsigned short* Cws    = (unsigned short*)(ws);               // 75,497,472

    hipLaunchKernelGGL(k1_ln_proj, dim3(4608), dim3(256), 0, stream,
                       e, mask, ln_w, ln_b, W_V, b_V, W_EG, b_EG, VtIn, VtOut, EGin, EGoutT);
    hipLaunchKernelGGL(k2_softmax, dim3(768), dim3(256), 0, stream, EGin, A_in);
    hipLaunchKernelGGL(k2_softmax, dim3(768), dim3(256), 0, stream, EGoutT, A_outT);
    hipLaunchKernelGGL(k2t_transpose, dim3(288, 16, 2), dim3(256), 0, stream,
                       VtIn, VtOut, VT2In, VT2Out);
    hipLaunchKernelGGL(k3_mfma, dim3(24, 3, 32), dim3(256), 0, stream,
                       A_in, VT2In, Cws);
    hipLaunchKernelGGL(k4_proj, dim3(3, 384, 2), dim3(256), 0, stream,
                       Cws, W_O, b_O, out);
}